// Round 12
// baseline (519.026 us; speedup 1.0000x reference)
//
#include <hip/hip_runtime.h>
#include <cmath>

#define DEV __device__ __forceinline__

typedef __bf16 bf16x8 __attribute__((ext_vector_type(8)));
typedef float f32x4v __attribute__((ext_vector_type(4)));
typedef unsigned short u16x8 __attribute__((ext_vector_type(8)));
typedef unsigned short u16x4 __attribute__((ext_vector_type(4)));

DEV float bf2f(unsigned short u){ return __uint_as_float(((unsigned)u)<<16); }
DEV unsigned short f2bf(float f){
  unsigned u = __float_as_uint(f);
  u = (u + 0x7fffu + ((u>>16)&1u)) >> 16;
  return (unsigned short)u;
}
// exact-GELU via branchless A&S 7.1.26 erf (|eps|<=1.5e-7) — R8-proven (~27us win vs erff)
DEV float geluf(float x){
  const float z = fabsf(x) * 0.70710678118654752f;
  const float t = __builtin_amdgcn_rcpf(1.0f + 0.3275911f*z);
  const float p = t*(0.254829592f + t*(-0.284496736f + t*(1.421413741f
                + t*(-1.453152027f + t*1.061405429f))));
  float er = 1.0f - p*__expf(-z*z);
  er = (x < 0.0f) ? -er : er;
  return 0.5f*x*(1.0f + er);
}

#define GLDS16(g,l) __builtin_amdgcn_global_load_lds(\
    (const __attribute__((address_space(1))) void*)(g), \
    (__attribute__((address_space(3))) void*)(l), 16, 0, 0)

// ---- problem constants ----
#define NB    4
#define NSEQ  2048
#define DDIM  512
#define MROWS 8192   // NB*NSEQ

// ---- workspace layout (bytes) ----
#define OFF_H     0u           // f32  8192x512   (16M)
#define OFF_HB    16777216u    // bf16 8192x512   (8M)
#define OFF_UV    25165824u    // bf16 8192x1024  (16M)  (prep: A2/B2 live here first)
#define OFF_GP    25165824u    // bf16 8192x512   (8M)   aliases UV (UV dead after geluacc)
#define OFF_R     33554432u    // bf16 8192x512   (8M)   aliases UV hi (dead after geluacc)
#define OFF_GSC   41943040u    // bf16 8192x512   (8M)
#define OFF_WUV   50331648u    // bf16 1024x512 (Wuv^T)
#define OFF_WP    51380224u    // bf16 512x1024 (Wp^T: [updW1_top^T | (msgW2@updW1_bot)^T])
#define OFF_WR    52428800u    // bf16 512x512  (updW2^T)
#define OFF_BUV   52953088u    // f32[1024]  (mb1 | zeros)
#define OFF_BP    52957184u    // f32[512]
#define OFF_BR    52959232u    // f32[512]
#define OFF_DOT   52961280u    // f32[8192] per-row halt-dot partials (32K)
#define OFF_SCAL  52994048u    // f32: [0..3] remaining, [4..7] w_step, [8] kl
#define OFF_FLAGS 52994112u    // int: [0] active, [1] done
// prep-only (aliases UV; dead before first gemm0 writes UV):
#define OFF_A2    25165824u    // bf16 512x512: (uW1_bot)^T
#define OFF_B2    25690112u    // bf16 512x512: mW2

// ================= prep: LDS-tiled 512x512 f32->bf16 transposes =================
__global__ __launch_bounds__(256) void k_prep_tr(
    const float* __restrict__ mW1, const float* __restrict__ uW2,
    const float* __restrict__ uW1,
    unsigned short* __restrict__ Wuv, unsigned short* __restrict__ Wr,
    unsigned short* __restrict__ Wp,  unsigned short* __restrict__ A2)
{
  __shared__ float t[64][65];
  const int tid = threadIdx.x, c = tid&63, r4 = tid>>6;
  const float* src; unsigned short* dst; int dld;
  switch (blockIdx.y){
    case 0: src = mW1;          dst = Wuv;          dld = 512;  break;
    case 1: src = mW1 + 262144; dst = Wuv + 262144; dld = 512;  break;
    case 2: src = uW2;          dst = Wr;           dld = 512;  break;
    case 3: src = uW1;          dst = Wp;           dld = 1024; break;
    default:src = uW1 + 262144; dst = A2;           dld = 512;  break;
  }
  const int k0 = (blockIdx.x>>3)<<6, n0 = (blockIdx.x&7)<<6;
  #pragma unroll
  for (int i=0;i<16;++i){ int r = i*4 + r4; t[r][c] = src[(size_t)(k0+r)*512 + n0 + c]; }
  __syncthreads();
  #pragma unroll
  for (int i=0;i<16;++i){ int r = i*4 + r4; dst[(size_t)(n0+r)*dld + k0 + c] = f2bf(t[c][r]); }
}

// merged misc prep: B2 copy | biasUV | biasR+state(+static kl for steps 0,1) | biasP
__global__ __launch_bounds__(256) void k_prep_misc(
    const float* __restrict__ mW2, const float* __restrict__ mb1,
    const float* __restrict__ ub2, const float* __restrict__ ub1,
    const float* __restrict__ mb2, const float* __restrict__ uW1,
    unsigned short* __restrict__ B2, float* __restrict__ biasUV,
    float* __restrict__ biasR, float* __restrict__ biasP,
    float* __restrict__ scal, int* __restrict__ flags, float kl01)
{
  const int bid = blockIdx.x, t = threadIdx.x;
  if (bid < 1024){
    int idx = bid*256 + t;
    B2[idx] = f2bf(mW2[idx]);
  } else if (bid == 1024){
    for (int i=t;i<1024;i+=256) biasUV[i] = (i<512)? mb1[i] : 0.f;
  } else if (bid == 1025){
    for (int i=t;i<512;i+=256) biasR[i] = ub2[i];
    if (t<4) scal[t]=1.f;
    else if (t<8) scal[t]=0.f;
    if (t==8) scal[8]=kl01;          // kl terms of steps 0,1 (halt==0 there -> static)
    if (t==9){ flags[0]=1; flags[1]=0; }
  } else {
    int n = (bid-1026)*256 + t;
    float s = ub1[n];
    for (int j=0;j<512;++j) s += mb2[j]*uW1[(512+j)*512+n];
    biasP[n] = s;
  }
}

__global__ __launch_bounds__(256) void k_init_h(
    const float* __restrict__ S, float* __restrict__ H, u16x4* __restrict__ Hb)
{
  size_t idx = (size_t)blockIdx.x*256 + threadIdx.x;   // float4 units, < 1048576
  float4 v = ((const float4*)S)[idx];
  ((float4*)H)[idx] = v;
  u16x4 o; o[0]=f2bf(v.x); o[1]=f2bf(v.y); o[2]=f2bf(v.z); o[3]=f2bf(v.w);
  Hb[idx] = o;
}

// ================= MFMA GEMM (128x64): prep-only path — R6-proven counted-vmcnt dbuf =========
template<int EPI>  // 0: bias+bf16 out, 1: bias+gelu+bf16 out
__global__ __launch_bounds__(256) void k_gemm(
    const unsigned short* __restrict__ A0, const unsigned short* __restrict__ A1,
    const unsigned short* __restrict__ Bt, const float* __restrict__ bias,
    void* __restrict__ Cout, int ldc, int ldb, int nK, int ksplit, int gridN,
    const int* __restrict__ flags)
{
  if (flags[0]==0) return;
  __shared__ unsigned short sm[2][12288];
  const int tid = threadIdx.x;
  const int bid = blockIdx.x;
  const int nb  = (int)gridDim.x;
  const int ppx = (nb>>3)/gridN;
  int mp, np;
  if (ppx*gridN*8 == nb){ const int xcd = bid&7, ib = bid>>3; mp = xcd*ppx + ib/gridN; np = ib%gridN; }
  else                  { mp = bid/gridN; np = bid%gridN; }
  const int m0 = mp<<7, n0 = np<<6;
  const int sr = tid>>3;
  const int scA = (((tid&7) ^ (sr&7)) << 3);
  const int lane = tid&63, wv = tid>>6, wr = wv>>1, wc = wv&1;
  const int la = lane&15, lg = lane>>4;
  const int swzr = (la&7)<<3;
  f32x4v acc[4][2] = {};

  auto stage = [&](int ks, int bufi){                  // 6 GLDS16 per thread
    const unsigned short* As = (ks<ksplit)? A0 : A1;
    const int kc = ((ks<ksplit)? ks : (ks-ksplit))<<6;
    unsigned short* s = sm[bufi];
    #pragma unroll
    for (int i=0;i<4;++i)
      GLDS16(As + (size_t)(m0 + i*32 + sr)*512 + kc + scA, s + i*2048 + tid*8);
    #pragma unroll
    for (int i=0;i<2;++i)
      GLDS16(Bt + (size_t)(n0 + i*32 + sr)*ldb + (ks<<6) + scA, s + 8192 + i*2048 + tid*8);
  };

  stage(0, 0);
  if (nK > 1) stage(1, 1);
  for (int ks=0; ks<nK; ++ks){
    const int cur = ks & 1;
    if (ks+1 < nK) asm volatile("s_waitcnt vmcnt(6)" ::: "memory");
    else           asm volatile("s_waitcnt vmcnt(0)" ::: "memory");
    __builtin_amdgcn_s_barrier();
    asm volatile("" ::: "memory");
    const unsigned short* s = sm[cur];
    #pragma unroll
    for (int kk=0;kk<2;++kk){
      bf16x8 af[4], bfr[2];
      #pragma unroll
      for (int mi=0;mi<4;++mi)
        af[mi] = *(const bf16x8*)(s + ((wr<<6) + (mi<<4) + la)*64 + (((kk<<5) + (lg<<3)) ^ swzr));
      #pragma unroll
      for (int ni=0;ni<2;++ni)
        bfr[ni] = *(const bf16x8*)(s + 8192 + ((wc<<5) + (ni<<4) + la)*64 + (((kk<<5) + (lg<<3)) ^ swzr));
      #pragma unroll
      for (int mi=0;mi<4;++mi)
        #pragma unroll
        for (int ni=0;ni<2;++ni)
          acc[mi][ni] = __builtin_amdgcn_mfma_f32_16x16x32_bf16(af[mi], bfr[ni], acc[mi][ni], 0, 0, 0);
    }
    asm volatile("" ::: "memory");
    __builtin_amdgcn_s_barrier();
    asm volatile("" ::: "memory");
    if (ks+2 < nK) stage(ks+2, cur);
  }

  const int r0 = m0 + (wr<<6) + (lg<<2);
  const int c0 = n0 + (wc<<5) + la;
  #pragma unroll
  for (int mi=0;mi<4;++mi){
    #pragma unroll
    for (int ni=0;ni<2;++ni){
      const int col = c0 + (ni<<4);
      const float bs = bias[col];
      #pragma unroll
      for (int r=0;r<4;++r){
        const int row = r0 + (mi<<4) + r;
        float v = acc[mi][ni][r] + bs;
        if constexpr (EPI==1) v = geluf(v);
        ((unsigned short*)Cout)[(size_t)row*ldc + col] = f2bf(v);
      }
    }
  }
}

// ================= MFMA GEMM (128x128): 64x64/wave, acc[4][4], ksplit A — main path =========
// 16 ds_read_b128 : 32 MFMA per K-step. dbuf 64KB LDS; counted-vmcnt(8) keeps the next
// tile's loads in flight across barriers (R6 pipeline). Works at 1-2 blocks/CU.
template<int EPI>  // 0: bias+bf16 out, 1: bias+gelu+bf16 out
__global__ __launch_bounds__(256) void k_gemm128(
    const unsigned short* __restrict__ A0, const unsigned short* __restrict__ A1,
    const unsigned short* __restrict__ Bt, const float* __restrict__ bias,
    unsigned short* __restrict__ Cout, int ldc, int ldb, int nK, int ksplit, int gridN,
    const int* __restrict__ flags)
{
  if (flags[0]==0) return;
  __shared__ unsigned short sm[2][16384];   // per buf: A 128x64 (8192) + B 128x64 (8192)
  const int tid = threadIdx.x;
  const int bid = blockIdx.x;
  const int nb  = (int)gridDim.x;
  const int ppx = (nb>>3)/gridN;
  int mp, np;
  if (ppx*gridN*8 == nb){ const int xcd = bid&7, ib = bid>>3; mp = xcd*ppx + ib/gridN; np = ib%gridN; }
  else                  { mp = bid/gridN; np = bid%gridN; }
  const int m0 = mp<<7, n0 = np<<7;
  const int sr = tid>>3;
  const int scA = (((tid&7) ^ (sr&7)) << 3);
  const int lane = tid&63, wv = tid>>6, wr = wv>>1, wc = wv&1;
  const int la = lane&15, lg = lane>>4;
  const int swzr = (la&7)<<3;
  f32x4v acc[4][4] = {};

  auto stage = [&](int ks, int bufi){                  // 8 GLDS16 per thread
    const unsigned short* As = (ks<ksplit)? A0 : A1;
    const int kc = ((ks<ksplit)? ks : (ks-ksplit))<<6;
    unsigned short* s = sm[bufi];
    #pragma unroll
    for (int i=0;i<4;++i)
      GLDS16(As + (size_t)(m0 + i*32 + sr)*512 + kc + scA, s + i*2048 + tid*8);
    #pragma unroll
    for (int i=0;i<4;++i)
      GLDS16(Bt + (size_t)(n0 + i*32 + sr)*ldb + (ks<<6) + scA, s + 8192 + i*2048 + tid*8);
  };

  stage(0, 0);
  if (nK > 1) stage(1, 1);
  for (int ks=0; ks<nK; ++ks){
    const int cur = ks & 1;
    if (ks+1 < nK) asm volatile("s_waitcnt vmcnt(8)" ::: "memory");
    else           asm volatile("s_waitcnt vmcnt(0)" ::: "memory");
    __builtin_amdgcn_s_barrier();
    asm volatile("" ::: "memory");
    const unsigned short* s = sm[cur];
    #pragma unroll
    for (int kk=0;kk<2;++kk){
      const int ko = ((kk<<5) + (lg<<3)) ^ swzr;
      bf16x8 af[4], bfr[4];
      #pragma unroll
      for (int mi=0;mi<4;++mi)
        af[mi] = *(const bf16x8*)(s + ((wr<<6) + (mi<<4) + la)*64 + ko);
      #pragma unroll
      for (int ni=0;ni<4;++ni)
        bfr[ni] = *(const bf16x8*)(s + 8192 + ((wc<<6) + (ni<<4) + la)*64 + ko);
      #pragma unroll
      for (int mi=0;mi<4;++mi)
        #pragma unroll
        for (int ni=0;ni<4;++ni)
          acc[mi][ni] = __builtin_amdgcn_mfma_f32_16x16x32_bf16(af[mi], bfr[ni], acc[mi][ni], 0, 0, 0);
    }
    asm volatile("" ::: "memory");
    __builtin_amdgcn_s_barrier();
    asm volatile("" ::: "memory");
    if (ks+2 < nK) stage(ks+2, cur);
  }

  const int r0 = m0 + (wr<<6) + (lg<<2);
  const int c0 = n0 + (wc<<6) + la;
  #pragma unroll
  for (int mi=0;mi<4;++mi){
    #pragma unroll
    for (int ni=0;ni<4;++ni){
      const int col = c0 + (ni<<4);
      const float bs = bias[col];
      #pragma unroll
      for (int r=0;r<4;++r){
        const int row = r0 + (mi<<4) + r;
        float v = acc[mi][ni][r] + bs;
        if constexpr (EPI==1) v = geluf(v);
        Cout[(size_t)row*ldc + col] = f2bf(v);
      }
    }
  }
}

// ================= G[i] = (sum_{d<=min(i,4)} gelu(U[i]+V[i-d])) / count =================
__global__ __launch_bounds__(256) void k_geluacc(
    const unsigned short* __restrict__ UV, unsigned short* __restrict__ G,
    const int* __restrict__ flags)
{
  if (flags[0]==0) return;
  int r = blockIdx.x*4 + (threadIdx.x>>6);
  int lane = threadIdx.x & 63;
  int c8 = lane*8;
  int i = r & (NSEQ-1);
  int nd = (i<4) ? i : 4;
  const u16x8 u = *(const u16x8*)(UV + (size_t)r*1024 + c8);
  float acc[8] = {0,0,0,0,0,0,0,0};
  for (int d=0; d<=nd; ++d){
    const u16x8 v = *(const u16x8*)(UV + (size_t)(r-d)*1024 + 512 + c8);
    #pragma unroll
    for (int j=0;j<8;++j) acc[j] += geluf(bf2f(u[j]) + bf2f(v[j]));
  }
  float inv = 1.0f/(float)(nd+1);
  u16x8 o;
  #pragma unroll
  for (int j=0;j<8;++j) o[j] = f2bf(acc[j]*inv);
  *(u16x8*)(G + (size_t)r*512 + c8) = o;
}

// ===== fused: OUT accum (prev step) + LayerNorm(h + R_bf16) + halt-dot partial =====
__global__ __launch_bounds__(256) void k_ln(
    const unsigned short* __restrict__ Rr, float* __restrict__ H, unsigned short* __restrict__ Hb,
    const float* __restrict__ gamma, const float* __restrict__ beta,
    const float* __restrict__ hW, float* __restrict__ DOT, float* __restrict__ OUT,
    const float* __restrict__ scal, const int* __restrict__ flags,
    int accmode, int dodot)
{
  const int lane = threadIdx.x & 63;
  const int row = (blockIdx.x<<2) + (threadIdx.x>>6);
  const int bidx = row >> 11;
  const size_t base = (size_t)row*512 + lane*8;
  float4 x0 = *(const float4*)(H+base);
  float4 x1 = *(const float4*)(H+base+4);

  if (accmode){                      // H still holds h_prev; w=0 once inactive
    const float w = scal[4+bidx];
    float4 o0, o1;
    if (accmode==1){
      o0 = make_float4(w*x0.x, w*x0.y, w*x0.z, w*x0.w);
      o1 = make_float4(w*x1.x, w*x1.y, w*x1.z, w*x1.w);
    } else {
      o0 = *(const float4*)(OUT+base);
      o1 = *(const float4*)(OUT+base+4);
      o0.x += w*x0.x; o0.y += w*x0.y; o0.z += w*x0.z; o0.w += w*x0.w;
      o1.x += w*x1.x; o1.y += w*x1.y; o1.z += w*x1.z; o1.w += w*x1.w;
    }
    *(float4*)(OUT+base)   = o0;
    *(float4*)(OUT+base+4) = o1;
  }
  if (flags[0]==0) return;

  const u16x8 rv = *(const u16x8*)(Rr+base);
  x0.x+=bf2f(rv[0]); x0.y+=bf2f(rv[1]); x0.z+=bf2f(rv[2]); x0.w+=bf2f(rv[3]);
  x1.x+=bf2f(rv[4]); x1.y+=bf2f(rv[5]); x1.z+=bf2f(rv[6]); x1.w+=bf2f(rv[7]);
  float s = x0.x+x0.y+x0.z+x0.w + x1.x+x1.y+x1.z+x1.w;
  float q = x0.x*x0.x+x0.y*x0.y+x0.z*x0.z+x0.w*x0.w
          + x1.x*x1.x+x1.y*x1.y+x1.z*x1.z+x1.w*x1.w;
  #pragma unroll
  for (int off=1; off<64; off<<=1){ s += __shfl_xor(s, off); q += __shfl_xor(q, off); }
  const float mean = s*(1.f/512.f);
  const float var  = q*(1.f/512.f) - mean*mean;
  const float rstd = rsqrtf(var + 1e-5f);
  float4 g0 = *(const float4*)(gamma + lane*8);
  float4 g1 = *(const float4*)(gamma + lane*8 + 4);
  float4 b0 = *(const float4*)(beta  + lane*8);
  float4 b1 = *(const float4*)(beta  + lane*8 + 4);
  float y[8];
  y[0]=(x0.x-mean)*rstd*g0.x+b0.x; y[1]=(x0.y-mean)*rstd*g0.y+b0.y;
  y[2]=(x0.z-mean)*rstd*g0.z+b0.z; y[3]=(x0.w-mean)*rstd*g0.w+b0.w;
  y[4]=(x1.x-mean)*rstd*g1.x+b1.x; y[5]=(x1.y-mean)*rstd*g1.y+b1.y;
  y[6]=(x1.z-mean)*rstd*g1.z+b1.z; y[7]=(x1.w-mean)*rstd*g1.w+b1.w;
  *(float4*)(H+base)   = make_float4(y[0],y[1],y[2],y[3]);
  *(float4*)(H+base+4) = make_float4(y[4],y[5],y[6],y[7]);
  u16x8 hb;
  #pragma unroll
  for (int j=0;j<8;++j) hb[j] = f2bf(y[j]);
  *(u16x8*)(Hb+base) = hb;

  if (dodot){
    float4 w0 = *(const float4*)(hW + lane*8);
    float4 w1 = *(const float4*)(hW + lane*8 + 4);
    float d = y[0]*w0.x + y[1]*w0.y + y[2]*w0.z + y[3]*w0.w
            + y[4]*w1.x + y[5]*w1.y + y[6]*w1.z + y[7]*w1.w;
    #pragma unroll
    for (int off=1; off<64; off<<=1) d += __shfl_xor(d, off);
    if (lane==0) DOT[row] = d;
  }
}

// ================= control: reduce DOT, halt / remaining / kl / done (steps >=2 only) =========
__global__ void k_control(const float* __restrict__ DOT, const float* __restrict__ hb,
                          float* __restrict__ scal, int* __restrict__ flags,
                          int step, float p, float logp, float* __restrict__ klout)
{
  __shared__ float hp[4];
  const int t = threadIdx.x, lane = t&63, b = t>>6;
  if (step>=2 && step<5){
    float s = 0.f;
    for (int i=lane; i<NSEQ; i+=64) s += DOT[b*NSEQ + i];
    #pragma unroll
    for (int off=1; off<64; off<<=1) s += __shfl_xor(s, off);
    if (lane==0) hp[b] = s;
  } else if (lane==0) hp[b] = 0.f;
  __syncthreads();
  if (t==0){
    bool active = flags[0]!=0;
    float halt[NB];
    for (int i=0;i<NB;++i){
      if (step < 2) halt[i]=0.f;
      else if (step == 5) halt[i]=1.f;
      else { float z = hp[i]*(1.f/2048.f) + hb[0]; halt[i] = 1.f/(1.f+expf(-z)); }
    }
    float hm = 0.25f*(halt[0]+halt[1]+halt[2]+halt[3]);
    if (active) scal[8] += p*(logp - logf(hm + 1e-8f));
    float mx = 0.f;
    for (int i=0;i<NB;++i){
      float rb = scal[i];
      float w  = active ? rb*halt[i] : 0.f;
      scal[4+i] = w;
      if (active) rb *= (1.f - halt[i]);
      scal[i] = rb;
      mx = fmaxf(mx, rb);
    }
    if (mx < 0.01f) flags[1] = 1;
    flags[0] = flags[1] ? 0 : 1;
    if (step==5) *klout = scal[8]*(1.0f/6.0f);
  }
}

// ================= OUT += w_b * H (final step only) =================
__global__ __launch_bounds__(256) void k_accum(
    const float* __restrict__ H, const float* __restrict__ scal, float* __restrict__ OUT)
{
  size_t idx = (size_t)blockIdx.x*256 + threadIdx.x;   // float4 units, < 1048576
  int b = (int)(idx >> 18);                            // 262144 float4 per batch
  float w = scal[4+b];
  float4 h = ((const float4*)H)[idx];
  float4 o = ((float4*)OUT)[idx];
  ((float4*)OUT)[idx] = make_float4(o.x+w*h.x, o.y+w*h.y, o.z+w*h.z, o.w+w*h.w);
}

extern "C" void kernel_launch(void* const* d_in, const int* in_sizes, int n_in,
                              void* d_out, int out_size, void* d_ws, size_t ws_size,
                              hipStream_t stream)
{
  const float* S   = (const float*)d_in[0];
  const float* mW1 = (const float*)d_in[1];
  const float* mb1 = (const float*)d_in[2];
  const float* mW2 = (const float*)d_in[3];
  const float* mb2 = (const float*)d_in[4];
  const float* uW1 = (const float*)d_in[5];
  const float* ub1 = (const float*)d_in[6];
  const float* uW2 = (const float*)d_in[7];
  const float* ub2 = (const float*)d_in[8];
  const float* hW  = (const float*)d_in[9];
  const float* hb  = (const float*)d_in[10];
  const float* lng = (const float*)d_in[11];
  const float* lnb = (const float*)d_in[12];

  char* ws = (char*)d_ws;
  float*          H     = (float*)(ws + OFF_H);
  unsigned short* Hb    = (unsigned short*)(ws + OFF_HB);
  unsigned short* UV    = (unsigned short*)(ws + OFF_UV);
  unsigned short* GP    = (unsigned short*)(ws + OFF_GP);
  unsigned short* GSC   = (unsigned short*)(ws + OFF_GSC);
  unsigned short* Rb16  = (unsigned short*)(ws + OFF_R);
  unsigned short* Wuv   = (unsigned short*)(ws + OFF_WUV);
  unsigned short* Wp    = (unsigned short*)(ws + OFF_WP);
  unsigned short* Wr    = (unsigned short*)(ws + OFF_WR);
  unsigned short* A2    = (unsigned short*)(ws + OFF_A2);
  unsigned short* B2    = (unsigned short*)(ws + OFF_B2);
  float*          biasUV= (float*)(ws + OFF_BUV);
  float*          biasP = (float*)(ws + OFF_BP);
  float*          biasR = (float*)(ws + OFF_BR);
  float*          DOT   = (float*)(ws + OFF_DOT);
  float*          scal  = (float*)(ws + OFF_SCAL);
  int*            flags = (int*)(ws + OFF_FLAGS);
  float*          OUT   = (float*)d_out;
  float*          klout = OUT + (size_t)NB*NSEQ*DDIM;

  // static kl terms for steps 0,1 (halt==0): p*(log p - log 1e-8)
  const double lg8 = log(1e-8);
  const float kl01 = (float)(0.2*(log(0.2)-lg8) + 0.16*(log(0.16)-lg8));

  // ---- state + weight prep (deterministic, inside the graph) ----
  k_prep_tr  <<<dim3(64,5), 256, 0, stream>>>(mW1, uW2, uW1, Wuv, Wr, Wp, A2);
  k_prep_misc<<<1028, 256, 0, stream>>>(mW2, mb1, ub2, ub1, mb2, uW1,
                                        B2, biasUV, biasR, biasP, scal, flags, kl01);
  // Wp upper K-half: (msgW2 @ updW1_bot)^T via MFMA; C[n][a] -> Wp[n*1024+512+a]
  k_gemm<0><<<32, 256, 0, stream>>>(A2, A2, B2, biasUV+512, Wp+512, 1024, 512, 8, 8, 8, flags);
  k_init_h   <<<4096, 256, 0, stream>>>(S, H, (u16x4*)Hb);

  for (int s = 0; s < 6; ++s){
    // UV = Hb @ [msgW1_top | msgW1_bot] (+b1 on U half) — 128x128, grid 512 (2 blocks/CU)
    k_gemm128<0><<<512, 256, 0, stream>>>(Hb, Hb, Wuv, biasUV, UV, 1024, 512, 8, 8, 8, flags);
    // G = windowed gelu-accumulate / counts
    k_geluacc<<<2048, 256, 0, stream>>>(UV, GSC, flags);
    // GP = gelu( Hb@updW1_top + GSC@(msgW2@updW1_bot) + biasP ) — 128x128, grid 256
    k_gemm128<1><<<256, 256, 0, stream>>>(Hb, GSC, Wp, biasP, GP, 512, 1024, 16, 8, 4, flags);
    // R = GP @ updW2 + upd_b2 (bf16) — 128x128, grid 256
    k_gemm128<0><<<256, 256, 0, stream>>>(GP, GP, Wr, biasR, Rb16, 512, 512, 8, 8, 4, flags);
    // OUT accum of h_{s-1}, then h = LN(h + R_bf16), then halt dot
    const int accmode = (s==3) ? 1 : (s>=4 ? 2 : 0);
    const int dodot   = (s>=2 && s<=4) ? 1 : 0;
    k_ln<<<2048, 256, 0, stream>>>(Rb16, H, Hb, lng, lnb, hW, DOT, OUT, scal, flags, accmode, dodot);
    if (s >= 2){
      float p  = 0.2f * (float)pow(0.8, (double)s);
      float lp = (float)log((double)p);
      k_control<<<1, 256, 0, stream>>>(DOT, hb, scal, flags, s, p, lp, klout);
    }
  }
  // final step's weighted h (w_5)
  k_accum<<<4096, 256, 0, stream>>>(H, scal, OUT);
}

// Round 13
// 502.767 us; speedup vs baseline: 1.0323x; 1.0323x over previous
//
#include <hip/hip_runtime.h>
#include <cmath>

#define DEV __device__ __forceinline__

typedef __bf16 bf16x8 __attribute__((ext_vector_type(8)));
typedef float f32x4v __attribute__((ext_vector_type(4)));
typedef unsigned short u16x8 __attribute__((ext_vector_type(8)));
typedef unsigned short u16x4 __attribute__((ext_vector_type(4)));

DEV float bf2f(unsigned short u){ return __uint_as_float(((unsigned)u)<<16); }
DEV unsigned short f2bf(float f){
  unsigned u = __float_as_uint(f);
  u = (u + 0x7fffu + ((u>>16)&1u)) >> 16;
  return (unsigned short)u;
}
// exact-GELU via branchless A&S 7.1.26 erf (|eps|<=1.5e-7) — R8-proven (~27us win vs erff)
DEV float geluf(float x){
  const float z = fabsf(x) * 0.70710678118654752f;
  const float t = __builtin_amdgcn_rcpf(1.0f + 0.3275911f*z);
  const float p = t*(0.254829592f + t*(-0.284496736f + t*(1.421413741f
                + t*(-1.453152027f + t*1.061405429f))));
  float er = 1.0f - p*__expf(-z*z);
  er = (x < 0.0f) ? -er : er;
  return 0.5f*x*(1.0f + er);
}

#define GLDS16(g,l) __builtin_amdgcn_global_load_lds(\
    (const __attribute__((address_space(1))) void*)(g), \
    (__attribute__((address_space(3))) void*)(l), 16, 0, 0)

// ---- problem constants ----
#define NB    4
#define NSEQ  2048
#define DDIM  512
#define MROWS 8192   // NB*NSEQ

// ---- workspace layout (bytes) ----
#define OFF_H     0u           // f32  8192x512   (16M)
#define OFF_HB    16777216u    // bf16 8192x512   (8M)
#define OFF_UV    25165824u    // bf16 8192x1024  (16M)  (prep: A2/B2 live here first)
#define OFF_GP    25165824u    // bf16 8192x512   (8M)   aliases UV (UV dead after geluacc)
#define OFF_R     33554432u    // bf16 8192x512   (8M)   aliases UV hi (dead after geluacc)
#define OFF_GSC   41943040u    // bf16 8192x512   (8M)
#define OFF_WUV   50331648u    // bf16 1024x512 (Wuv^T)
#define OFF_WP    51380224u    // bf16 512x1024 (Wp^T: [updW1_top^T | (msgW2@updW1_bot)^T])
#define OFF_WR    52428800u    // bf16 512x512  (updW2^T)
#define OFF_BUV   52953088u    // f32[1024]  (mb1 | zeros)
#define OFF_BP    52957184u    // f32[512]
#define OFF_BR    52959232u    // f32[512]
#define OFF_DOT   52961280u    // f32[8192] per-row halt-dot partials (32K)
#define OFF_SCAL  52994048u    // f32: [0..3] remaining, [4..7] w_step, [8] kl
#define OFF_FLAGS 52994112u    // int: [0] active, [1] done
// prep-only (aliases UV; dead before first gemm0 writes UV):
#define OFF_A2    25165824u    // bf16 512x512: (uW1_bot)^T
#define OFF_B2    25690112u    // bf16 512x512: mW2

// ================= prep: LDS-tiled 512x512 f32->bf16 transposes =================
__global__ __launch_bounds__(256) void k_prep_tr(
    const float* __restrict__ mW1, const float* __restrict__ uW2,
    const float* __restrict__ uW1,
    unsigned short* __restrict__ Wuv, unsigned short* __restrict__ Wr,
    unsigned short* __restrict__ Wp,  unsigned short* __restrict__ A2)
{
  __shared__ float t[64][65];
  const int tid = threadIdx.x, c = tid&63, r4 = tid>>6;
  const float* src; unsigned short* dst; int dld;
  switch (blockIdx.y){
    case 0: src = mW1;          dst = Wuv;          dld = 512;  break;
    case 1: src = mW1 + 262144; dst = Wuv + 262144; dld = 512;  break;
    case 2: src = uW2;          dst = Wr;           dld = 512;  break;
    case 3: src = uW1;          dst = Wp;           dld = 1024; break;
    default:src = uW1 + 262144; dst = A2;           dld = 512;  break;
  }
  const int k0 = (blockIdx.x>>3)<<6, n0 = (blockIdx.x&7)<<6;
  #pragma unroll
  for (int i=0;i<16;++i){ int r = i*4 + r4; t[r][c] = src[(size_t)(k0+r)*512 + n0 + c]; }
  __syncthreads();
  #pragma unroll
  for (int i=0;i<16;++i){ int r = i*4 + r4; dst[(size_t)(n0+r)*dld + k0 + c] = f2bf(t[c][r]); }
}

// merged misc prep: B2 copy | biasUV | biasR+state(+static kl for steps 0,1) | biasP
__global__ __launch_bounds__(256) void k_prep_misc(
    const float* __restrict__ mW2, const float* __restrict__ mb1,
    const float* __restrict__ ub2, const float* __restrict__ ub1,
    const float* __restrict__ mb2, const float* __restrict__ uW1,
    unsigned short* __restrict__ B2, float* __restrict__ biasUV,
    float* __restrict__ biasR, float* __restrict__ biasP,
    float* __restrict__ scal, int* __restrict__ flags, float kl01)
{
  const int bid = blockIdx.x, t = threadIdx.x;
  if (bid < 1024){
    int idx = bid*256 + t;
    B2[idx] = f2bf(mW2[idx]);
  } else if (bid == 1024){
    for (int i=t;i<1024;i+=256) biasUV[i] = (i<512)? mb1[i] : 0.f;
  } else if (bid == 1025){
    for (int i=t;i<512;i+=256) biasR[i] = ub2[i];
    if (t<4) scal[t]=1.f;
    else if (t<8) scal[t]=0.f;
    if (t==8) scal[8]=kl01;          // kl terms of steps 0,1 (halt==0 there -> static)
    if (t==9){ flags[0]=1; flags[1]=0; }
  } else {
    int n = (bid-1026)*256 + t;
    float s = ub1[n];
    for (int j=0;j<512;++j) s += mb2[j]*uW1[(512+j)*512+n];
    biasP[n] = s;
  }
}

__global__ __launch_bounds__(256) void k_init_h(
    const float* __restrict__ S, float* __restrict__ H, u16x4* __restrict__ Hb)
{
  size_t idx = (size_t)blockIdx.x*256 + threadIdx.x;   // float4 units, < 1048576
  float4 v = ((const float4*)S)[idx];
  ((float4*)H)[idx] = v;
  u16x4 o; o[0]=f2bf(v.x); o[1]=f2bf(v.y); o[2]=f2bf(v.z); o[3]=f2bf(v.w);
  Hb[idx] = o;
}

// ================= MFMA GEMM (128x64): gemm1/gemm2/prep — R6-proven counted-vmcnt dbuf =========
// Needs >=2 blocks/CU (grid>=512): cross-block overlap hides the stage latency (R12 lesson).
template<int EPI>  // 0: bias+bf16 out, 1: bias+gelu+bf16 out
__global__ __launch_bounds__(256) void k_gemm(
    const unsigned short* __restrict__ A0, const unsigned short* __restrict__ A1,
    const unsigned short* __restrict__ Bt, const float* __restrict__ bias,
    void* __restrict__ Cout, int ldc, int ldb, int nK, int ksplit, int gridN,
    const int* __restrict__ flags)
{
  if (flags[0]==0) return;
  __shared__ unsigned short sm[2][12288];
  const int tid = threadIdx.x;
  const int bid = blockIdx.x;
  const int nb  = (int)gridDim.x;
  const int ppx = (nb>>3)/gridN;
  int mp, np;
  if (ppx*gridN*8 == nb){ const int xcd = bid&7, ib = bid>>3; mp = xcd*ppx + ib/gridN; np = ib%gridN; }
  else                  { mp = bid/gridN; np = bid%gridN; }
  const int m0 = mp<<7, n0 = np<<6;
  const int sr = tid>>3;
  const int scA = (((tid&7) ^ (sr&7)) << 3);
  const int lane = tid&63, wv = tid>>6, wr = wv>>1, wc = wv&1;
  const int la = lane&15, lg = lane>>4;
  const int swzr = (la&7)<<3;
  f32x4v acc[4][2] = {};

  auto stage = [&](int ks, int bufi){                  // 6 GLDS16 per thread
    const unsigned short* As = (ks<ksplit)? A0 : A1;
    const int kc = ((ks<ksplit)? ks : (ks-ksplit))<<6;
    unsigned short* s = sm[bufi];
    #pragma unroll
    for (int i=0;i<4;++i)
      GLDS16(As + (size_t)(m0 + i*32 + sr)*512 + kc + scA, s + i*2048 + tid*8);
    #pragma unroll
    for (int i=0;i<2;++i)
      GLDS16(Bt + (size_t)(n0 + i*32 + sr)*ldb + (ks<<6) + scA, s + 8192 + i*2048 + tid*8);
  };

  stage(0, 0);
  if (nK > 1) stage(1, 1);
  for (int ks=0; ks<nK; ++ks){
    const int cur = ks & 1;
    if (ks+1 < nK) asm volatile("s_waitcnt vmcnt(6)" ::: "memory");
    else           asm volatile("s_waitcnt vmcnt(0)" ::: "memory");
    __builtin_amdgcn_s_barrier();
    asm volatile("" ::: "memory");
    const unsigned short* s = sm[cur];
    #pragma unroll
    for (int kk=0;kk<2;++kk){
      bf16x8 af[4], bfr[2];
      #pragma unroll
      for (int mi=0;mi<4;++mi)
        af[mi] = *(const bf16x8*)(s + ((wr<<6) + (mi<<4) + la)*64 + (((kk<<5) + (lg<<3)) ^ swzr));
      #pragma unroll
      for (int ni=0;ni<2;++ni)
        bfr[ni] = *(const bf16x8*)(s + 8192 + ((wc<<5) + (ni<<4) + la)*64 + (((kk<<5) + (lg<<3)) ^ swzr));
      #pragma unroll
      for (int mi=0;mi<4;++mi)
        #pragma unroll
        for (int ni=0;ni<2;++ni)
          acc[mi][ni] = __builtin_amdgcn_mfma_f32_16x16x32_bf16(af[mi], bfr[ni], acc[mi][ni], 0, 0, 0);
    }
    asm volatile("" ::: "memory");
    __builtin_amdgcn_s_barrier();
    asm volatile("" ::: "memory");
    if (ks+2 < nK) stage(ks+2, cur);
  }

  const int r0 = m0 + (wr<<6) + (lg<<2);
  const int c0 = n0 + (wc<<5) + la;
  #pragma unroll
  for (int mi=0;mi<4;++mi){
    #pragma unroll
    for (int ni=0;ni<2;++ni){
      const int col = c0 + (ni<<4);
      const float bs = bias[col];
      #pragma unroll
      for (int r=0;r<4;++r){
        const int row = r0 + (mi<<4) + r;
        float v = acc[mi][ni][r] + bs;
        if constexpr (EPI==1) v = geluf(v);
        ((unsigned short*)Cout)[(size_t)row*ldc + col] = f2bf(v);
      }
    }
  }
}

// ================= MFMA GEMM (128x128): gemm0 only (grid 512 = 2 blocks/CU) =================
// 16 ds_read_b128 : 32 MFMA per K-step; dbuf 64KB; counted-vmcnt(8) pipeline.
__global__ __launch_bounds__(256) void k_gemm128(
    const unsigned short* __restrict__ A0,
    const unsigned short* __restrict__ Bt, const float* __restrict__ bias,
    unsigned short* __restrict__ Cout, int ldc, int ldb, int nK, int gridN,
    const int* __restrict__ flags)
{
  if (flags[0]==0) return;
  __shared__ unsigned short sm[2][16384];   // per buf: A 128x64 (8192) + B 128x64 (8192)
  const int tid = threadIdx.x;
  const int bid = blockIdx.x;
  const int nb  = (int)gridDim.x;
  const int ppx = (nb>>3)/gridN;
  int mp, np;
  if (ppx*gridN*8 == nb){ const int xcd = bid&7, ib = bid>>3; mp = xcd*ppx + ib/gridN; np = ib%gridN; }
  else                  { mp = bid/gridN; np = bid%gridN; }
  const int m0 = mp<<7, n0 = np<<7;
  const int sr = tid>>3;
  const int scA = (((tid&7) ^ (sr&7)) << 3);
  const int lane = tid&63, wv = tid>>6, wr = wv>>1, wc = wv&1;
  const int la = lane&15, lg = lane>>4;
  const int swzr = (la&7)<<3;
  f32x4v acc[4][4] = {};

  auto stage = [&](int ks, int bufi){                  // 8 GLDS16 per thread
    const int kc = ks<<6;
    unsigned short* s = sm[bufi];
    #pragma unroll
    for (int i=0;i<4;++i)
      GLDS16(A0 + (size_t)(m0 + i*32 + sr)*512 + kc + scA, s + i*2048 + tid*8);
    #pragma unroll
    for (int i=0;i<4;++i)
      GLDS16(Bt + (size_t)(n0 + i*32 + sr)*ldb + kc + scA, s + 8192 + i*2048 + tid*8);
  };

  stage(0, 0);
  if (nK > 1) stage(1, 1);
  for (int ks=0; ks<nK; ++ks){
    const int cur = ks & 1;
    if (ks+1 < nK) asm volatile("s_waitcnt vmcnt(8)" ::: "memory");
    else           asm volatile("s_waitcnt vmcnt(0)" ::: "memory");
    __builtin_amdgcn_s_barrier();
    asm volatile("" ::: "memory");
    const unsigned short* s = sm[cur];
    #pragma unroll
    for (int kk=0;kk<2;++kk){
      const int ko = ((kk<<5) + (lg<<3)) ^ swzr;
      bf16x8 af[4], bfr[4];
      #pragma unroll
      for (int mi=0;mi<4;++mi)
        af[mi] = *(const bf16x8*)(s + ((wr<<6) + (mi<<4) + la)*64 + ko);
      #pragma unroll
      for (int ni=0;ni<4;++ni)
        bfr[ni] = *(const bf16x8*)(s + 8192 + ((wc<<6) + (ni<<4) + la)*64 + ko);
      #pragma unroll
      for (int mi=0;mi<4;++mi)
        #pragma unroll
        for (int ni=0;ni<4;++ni)
          acc[mi][ni] = __builtin_amdgcn_mfma_f32_16x16x32_bf16(af[mi], bfr[ni], acc[mi][ni], 0, 0, 0);
    }
    asm volatile("" ::: "memory");
    __builtin_amdgcn_s_barrier();
    asm volatile("" ::: "memory");
    if (ks+2 < nK) stage(ks+2, cur);
  }

  const int r0 = m0 + (wr<<6) + (lg<<2);
  const int c0 = n0 + (wc<<6) + la;
  #pragma unroll
  for (int mi=0;mi<4;++mi){
    #pragma unroll
    for (int ni=0;ni<4;++ni){
      const int col = c0 + (ni<<4);
      const float bs = bias[col];
      #pragma unroll
      for (int r=0;r<4;++r){
        const int row = r0 + (mi<<4) + r;
        Cout[(size_t)row*ldc + col] = f2bf(acc[mi][ni][r] + bs);
      }
    }
  }
}

// ================= G[i] = (sum_{d<=min(i,4)} gelu(U[i]+V[i-d])) / count =================
__global__ __launch_bounds__(256) void k_geluacc(
    const unsigned short* __restrict__ UV, unsigned short* __restrict__ G,
    const int* __restrict__ flags)
{
  if (flags[0]==0) return;
  int r = blockIdx.x*4 + (threadIdx.x>>6);
  int lane = threadIdx.x & 63;
  int c8 = lane*8;
  int i = r & (NSEQ-1);
  int nd = (i<4) ? i : 4;
  const u16x8 u = *(const u16x8*)(UV + (size_t)r*1024 + c8);
  float acc[8] = {0,0,0,0,0,0,0,0};
  for (int d=0; d<=nd; ++d){
    const u16x8 v = *(const u16x8*)(UV + (size_t)(r-d)*1024 + 512 + c8);
    #pragma unroll
    for (int j=0;j<8;++j) acc[j] += geluf(bf2f(u[j]) + bf2f(v[j]));
  }
  float inv = 1.0f/(float)(nd+1);
  u16x8 o;
  #pragma unroll
  for (int j=0;j<8;++j) o[j] = f2bf(acc[j]*inv);
  *(u16x8*)(G + (size_t)r*512 + c8) = o;
}

// ===== fused: OUT accum (prev step) + LayerNorm(h + R_bf16) + halt-dot partial =====
__global__ __launch_bounds__(256) void k_ln(
    const unsigned short* __restrict__ Rr, float* __restrict__ H, unsigned short* __restrict__ Hb,
    const float* __restrict__ gamma, const float* __restrict__ beta,
    const float* __restrict__ hW, float* __restrict__ DOT, float* __restrict__ OUT,
    const float* __restrict__ scal, const int* __restrict__ flags,
    int accmode, int dodot)
{
  const int lane = threadIdx.x & 63;
  const int row = (blockIdx.x<<2) + (threadIdx.x>>6);
  const int bidx = row >> 11;
  const size_t base = (size_t)row*512 + lane*8;
  float4 x0 = *(const float4*)(H+base);
  float4 x1 = *(const float4*)(H+base+4);

  if (accmode){                      // H still holds h_prev; w=0 once inactive
    const float w = scal[4+bidx];
    float4 o0, o1;
    if (accmode==1){
      o0 = make_float4(w*x0.x, w*x0.y, w*x0.z, w*x0.w);
      o1 = make_float4(w*x1.x, w*x1.y, w*x1.z, w*x1.w);
    } else {
      o0 = *(const float4*)(OUT+base);
      o1 = *(const float4*)(OUT+base+4);
      o0.x += w*x0.x; o0.y += w*x0.y; o0.z += w*x0.z; o0.w += w*x0.w;
      o1.x += w*x1.x; o1.y += w*x1.y; o1.z += w*x1.z; o1.w += w*x1.w;
    }
    *(float4*)(OUT+base)   = o0;
    *(float4*)(OUT+base+4) = o1;
  }
  if (flags[0]==0) return;

  const u16x8 rv = *(const u16x8*)(Rr+base);
  x0.x+=bf2f(rv[0]); x0.y+=bf2f(rv[1]); x0.z+=bf2f(rv[2]); x0.w+=bf2f(rv[3]);
  x1.x+=bf2f(rv[4]); x1.y+=bf2f(rv[5]); x1.z+=bf2f(rv[6]); x1.w+=bf2f(rv[7]);
  float s = x0.x+x0.y+x0.z+x0.w + x1.x+x1.y+x1.z+x1.w;
  float q = x0.x*x0.x+x0.y*x0.y+x0.z*x0.z+x0.w*x0.w
          + x1.x*x1.x+x1.y*x1.y+x1.z*x1.z+x1.w*x1.w;
  #pragma unroll
  for (int off=1; off<64; off<<=1){ s += __shfl_xor(s, off); q += __shfl_xor(q, off); }
  const float mean = s*(1.f/512.f);
  const float var  = q*(1.f/512.f) - mean*mean;
  const float rstd = rsqrtf(var + 1e-5f);
  float4 g0 = *(const float4*)(gamma + lane*8);
  float4 g1 = *(const float4*)(gamma + lane*8 + 4);
  float4 b0 = *(const float4*)(beta  + lane*8);
  float4 b1 = *(const float4*)(beta  + lane*8 + 4);
  float y[8];
  y[0]=(x0.x-mean)*rstd*g0.x+b0.x; y[1]=(x0.y-mean)*rstd*g0.y+b0.y;
  y[2]=(x0.z-mean)*rstd*g0.z+b0.z; y[3]=(x0.w-mean)*rstd*g0.w+b0.w;
  y[4]=(x1.x-mean)*rstd*g1.x+b1.x; y[5]=(x1.y-mean)*rstd*g1.y+b1.y;
  y[6]=(x1.z-mean)*rstd*g1.z+b1.z; y[7]=(x1.w-mean)*rstd*g1.w+b1.w;
  *(float4*)(H+base)   = make_float4(y[0],y[1],y[2],y[3]);
  *(float4*)(H+base+4) = make_float4(y[4],y[5],y[6],y[7]);
  u16x8 hb;
  #pragma unroll
  for (int j=0;j<8;++j) hb[j] = f2bf(y[j]);
  *(u16x8*)(Hb+base) = hb;

  if (dodot){
    float4 w0 = *(const float4*)(hW + lane*8);
    float4 w1 = *(const float4*)(hW + lane*8 + 4);
    float d = y[0]*w0.x + y[1]*w0.y + y[2]*w0.z + y[3]*w0.w
            + y[4]*w1.x + y[5]*w1.y + y[6]*w1.z + y[7]*w1.w;
    #pragma unroll
    for (int off=1; off<64; off<<=1) d += __shfl_xor(d, off);
    if (lane==0) DOT[row] = d;
  }
}

// ================= control: reduce DOT, halt / remaining / kl / done (steps 2..4 only) ========
__global__ void k_control(const float* __restrict__ DOT, const float* __restrict__ hb,
                          float* __restrict__ scal, int* __restrict__ flags,
                          int step, float p, float logp)
{
  __shared__ float hp[4];
  const int t = threadIdx.x, lane = t&63, b = t>>6;
  {
    float s = 0.f;
    for (int i=lane; i<NSEQ; i+=64) s += DOT[b*NSEQ + i];
    #pragma unroll
    for (int off=1; off<64; off<<=1) s += __shfl_xor(s, off);
    if (lane==0) hp[b] = s;
  }
  __syncthreads();
  if (t==0){
    bool active = flags[0]!=0;
    float halt[NB];
    for (int i=0;i<NB;++i){
      float z = hp[i]*(1.f/2048.f) + hb[0];
      halt[i] = 1.f/(1.f+expf(-z));
    }
    float hm = 0.25f*(halt[0]+halt[1]+halt[2]+halt[3]);
    if (active) scal[8] += p*(logp - logf(hm + 1e-8f));
    float mx = 0.f;
    for (int i=0;i<NB;++i){
      float rb = scal[i];
      float w  = active ? rb*halt[i] : 0.f;
      scal[4+i] = w;
      if (active) rb *= (1.f - halt[i]);
      scal[i] = rb;
      mx = fmaxf(mx, rb);
    }
    if (mx < 0.01f) flags[1] = 1;
    flags[0] = flags[1] ? 0 : 1;
  }
}

// ======= final step (s=5): halt==1 -> w = remaining*active; kl term static; write klout =======
__global__ __launch_bounds__(256) void k_accum(
    const float* __restrict__ H, const float* __restrict__ scal,
    const int* __restrict__ flags, float* __restrict__ OUT,
    float* __restrict__ klout, float kl5)
{
  size_t idx = (size_t)blockIdx.x*256 + threadIdx.x;   // float4 units, < 1048576
  const bool active = flags[0]!=0;
  int b = (int)(idx >> 18);                            // 262144 float4 per batch
  float w = active ? scal[b] : 0.f;                    // remaining * halt(=1)
  float4 h = ((const float4*)H)[idx];
  float4 o = ((float4*)OUT)[idx];
  ((float4*)OUT)[idx] = make_float4(o.x+w*h.x, o.y+w*h.y, o.z+w*h.z, o.w+w*h.w);
  if (idx==0){
    float k = scal[8];
    if (active) k += kl5;                              // p5*(log p5 - log(1+1e-8)) = p5*log p5 in f32
    *klout = k*(1.0f/6.0f);
  }
}

extern "C" void kernel_launch(void* const* d_in, const int* in_sizes, int n_in,
                              void* d_out, int out_size, void* d_ws, size_t ws_size,
                              hipStream_t stream)
{
  const float* S   = (const float*)d_in[0];
  const float* mW1 = (const float*)d_in[1];
  const float* mb1 = (const float*)d_in[2];
  const float* mW2 = (const float*)d_in[3];
  const float* mb2 = (const float*)d_in[4];
  const float* uW1 = (const float*)d_in[5];
  const float* ub1 = (const float*)d_in[6];
  const float* uW2 = (const float*)d_in[7];
  const float* ub2 = (const float*)d_in[8];
  const float* hW  = (const float*)d_in[9];
  const float* hb  = (const float*)d_in[10];
  const float* lng = (const float*)d_in[11];
  const float* lnb = (const float*)d_in[12];

  char* ws = (char*)d_ws;
  float*          H     = (float*)(ws + OFF_H);
  unsigned short* Hb    = (unsigned short*)(ws + OFF_HB);
  unsigned short* UV    = (unsigned short*)(ws + OFF_UV);
  unsigned short* GP    = (unsigned short*)(ws + OFF_GP);
  unsigned short* GSC   = (unsigned short*)(ws + OFF_GSC);
  unsigned short* Rb16  = (unsigned short*)(ws + OFF_R);
  unsigned short* Wuv   = (unsigned short*)(ws + OFF_WUV);
  unsigned short* Wp    = (unsigned short*)(ws + OFF_WP);
  unsigned short* Wr    = (unsigned short*)(ws + OFF_WR);
  unsigned short* A2    = (unsigned short*)(ws + OFF_A2);
  unsigned short* B2    = (unsigned short*)(ws + OFF_B2);
  float*          biasUV= (float*)(ws + OFF_BUV);
  float*          biasP = (float*)(ws + OFF_BP);
  float*          biasR = (float*)(ws + OFF_BR);
  float*          DOT   = (float*)(ws + OFF_DOT);
  float*          scal  = (float*)(ws + OFF_SCAL);
  int*            flags = (int*)(ws + OFF_FLAGS);
  float*          OUT   = (float*)d_out;
  float*          klout = OUT + (size_t)NB*NSEQ*DDIM;

  // static kl terms: steps 0,1 (halt==0) and step 5 (halt==1 -> log(1+1e-8)=0 in f32)
  const double lg8 = log(1e-8);
  const float kl01 = (float)(0.2*(log(0.2)-lg8) + 0.16*(log(0.16)-lg8));
  const double p5  = 0.2*pow(0.8, 5.0);
  const float kl5  = (float)(p5*log(p5));

  // ---- state + weight prep (deterministic, inside the graph) ----
  k_prep_tr  <<<dim3(64,5), 256, 0, stream>>>(mW1, uW2, uW1, Wuv, Wr, Wp, A2);
  k_prep_misc<<<1028, 256, 0, stream>>>(mW2, mb1, ub2, ub1, mb2, uW1,
                                        B2, biasUV, biasR, biasP, scal, flags, kl01);
  // Wp upper K-half: (msgW2 @ updW1_bot)^T via MFMA; C[n][a] -> Wp[n*1024+512+a]
  k_gemm<0><<<32, 256, 0, stream>>>(A2, A2, B2, biasUV+512, Wp+512, 1024, 512, 8, 8, 8, flags);
  k_init_h   <<<4096, 256, 0, stream>>>(S, H, (u16x4*)Hb);

  for (int s = 0; s < 6; ++s){
    // UV = Hb @ [msgW1_top | msgW1_bot] (+b1 on U half) — 128x128, grid 512 (2 blocks/CU)
    k_gemm128<<<512, 256, 0, stream>>>(Hb, Wuv, biasUV, UV, 1024, 512, 8, 8, flags);
    // G = windowed gelu-accumulate / counts
    k_geluacc<<<2048, 256, 0, stream>>>(UV, GSC, flags);
    // GP = gelu( Hb@updW1_top + GSC@(msgW2@updW1_bot) + biasP ) — 128x64, grid 512
    k_gemm<1><<<512, 256, 0, stream>>>(Hb, GSC, Wp, biasP, GP, 512, 1024, 16, 8, 8, flags);
    // R = GP @ updW2 + upd_b2 (bf16) — 128x64, grid 512
    k_gemm<0><<<512, 256, 0, stream>>>(GP, GP, Wr, biasR, Rb16, 512, 512, 8, 8, 8, flags);
    // OUT accum of h_{s-1}, then h = LN(h + R_bf16), then halt dot
    const int accmode = (s==3) ? 1 : (s>=4 ? 2 : 0);
    const int dodot   = (s>=2 && s<=4) ? 1 : 0;
    k_ln<<<2048, 256, 0, stream>>>(Rb16, H, Hb, lng, lnb, hW, DOT, OUT, scal, flags, accmode, dodot);
    if (s >= 2 && s <= 4){
      float p  = 0.2f * (float)pow(0.8, (double)s);
      float lp = (float)log((double)p);
      k_control<<<1, 256, 0, stream>>>(DOT, hb, scal, flags, s, p, lp);
    }
  }
  // final step's weighted h (w_5 = remaining) + klout (static kl term)
  k_accum<<<4096, 256, 0, stream>>>(H, scal, flags, OUT, klout, kl5);
}